// Round 4
// baseline (539.629 us; speedup 1.0000x reference)
//
#include <hip/hip_runtime.h>
#include <hip/hip_bf16.h>

// Problem constants (fixed by setup_inputs)
constexpr int TDIM = 16384;
constexpr int DIN  = 4096;
constexpr int DOUT = 4096;
constexpr int RNK  = 32;
constexpr float EPSF = 1e-8f;

using i32x4 = __attribute__((ext_vector_type(4))) int;

// ---------------------------------------------------------------------------
// Kernel 1: weight_eff = W + loraB @ loraA  -> per-row absmax -> int8 quantize
// (unchanged from round 2)
// ---------------------------------------------------------------------------
__global__ __launch_bounds__(256)
void wquant_kernel(const float* __restrict__ W,
                   const float* __restrict__ Amat,   // [32, 4096]
                   const float* __restrict__ Bmat,   // [4096, 32]
                   float* __restrict__ a_w,          // [4096]
                   signed char* __restrict__ qw)     // [4096, 4096]
{
    const int tid = threadIdx.x;
    const int o0  = blockIdx.x * 4;

    __shared__ float Bsh[4][32];
    __shared__ float red[4][4];
    __shared__ float awsh[4];

    if (tid < 128) {
        int r = tid >> 5, c = tid & 31;
        Bsh[r][c] = Bmat[(size_t)(o0 + r) * RNK + c];
    }
    __syncthreads();

    float4 acc[4][4];
    #pragma unroll
    for (int r = 0; r < 4; ++r)
        #pragma unroll
        for (int c = 0; c < 4; ++c)
            acc[r][c] = *(const float4*)(W + (size_t)(o0 + r) * DIN + c * 1024 + tid * 4);

    #pragma unroll 4
    for (int k = 0; k < RNK; ++k) {
        float4 a[4];
        #pragma unroll
        for (int c = 0; c < 4; ++c)
            a[c] = *(const float4*)(Amat + (size_t)k * DIN + c * 1024 + tid * 4);
        #pragma unroll
        for (int r = 0; r < 4; ++r) {
            const float b = Bsh[r][k];
            #pragma unroll
            for (int c = 0; c < 4; ++c) {
                acc[r][c].x += b * a[c].x; acc[r][c].y += b * a[c].y;
                acc[r][c].z += b * a[c].z; acc[r][c].w += b * a[c].w;
            }
        }
    }

    const int wid = tid >> 6;
    #pragma unroll
    for (int r = 0; r < 4; ++r) {
        float m = 0.f;
        #pragma unroll
        for (int c = 0; c < 4; ++c) {
            float4 v = acc[r][c];
            m = fmaxf(m, fmaxf(fmaxf(fabsf(v.x), fabsf(v.y)),
                               fmaxf(fabsf(v.z), fabsf(v.w))));
        }
        for (int off = 1; off < 64; off <<= 1)
            m = fmaxf(m, __shfl_xor(m, off));
        if ((tid & 63) == 0) red[wid][r] = m;
    }
    __syncthreads();
    if (tid < 4) {
        float m = fmaxf(fmaxf(red[0][tid], red[1][tid]),
                        fmaxf(red[2][tid], red[3][tid]));
        float aw = m + EPSF;
        awsh[tid] = aw;
        a_w[o0 + tid] = aw;
    }
    __syncthreads();

    #pragma unroll
    for (int r = 0; r < 4; ++r) {
        const float aw = awsh[r];
        #pragma unroll
        for (int c = 0; c < 4; ++c) {
            float4 v = acc[r][c];
            int q0 = __float2int_rn((v.x / aw) * 127.0f);
            int q1 = __float2int_rn((v.y / aw) * 127.0f);
            int q2 = __float2int_rn((v.z / aw) * 127.0f);
            int q3 = __float2int_rn((v.w / aw) * 127.0f);
            unsigned int packed = (q0 & 0xff) | ((q1 & 0xff) << 8) |
                                  ((q2 & 0xff) << 16) | ((q3 & 0xff) << 24);
            *(unsigned int*)(qw + (size_t)(o0 + r) * DIN + c * 1024 + tid * 4) = packed;
        }
    }
}

// ---------------------------------------------------------------------------
// Kernel 2: x quantize (unchanged from round 2 — coalesced)
// ---------------------------------------------------------------------------
__global__ __launch_bounds__(256)
void xquant_kernel(const float* __restrict__ x,
                   const float* __restrict__ axp,
                   unsigned int* __restrict__ qx)
{
    const float inv = 1.0f / fmaxf(axp[0], EPSF);
    const size_t base = (size_t)blockIdx.x * 1024 + threadIdx.x;
    const float4* xv = (const float4*)x;

    float4 v[4];
    #pragma unroll
    for (int j = 0; j < 4; ++j)
        v[j] = xv[base + j * 256];

    #pragma unroll
    for (int j = 0; j < 4; ++j) {
        int q0 = __float2int_rn(fminf(fmaxf(v[j].x * inv, -1.f), 1.f) * 127.0f);
        int q1 = __float2int_rn(fminf(fmaxf(v[j].y * inv, -1.f), 1.f) * 127.0f);
        int q2 = __float2int_rn(fminf(fmaxf(v[j].z * inv, -1.f), 1.f) * 127.0f);
        int q3 = __float2int_rn(fminf(fmaxf(v[j].w * inv, -1.f), 1.f) * 127.0f);
        qx[base + j * 256] = (q0 & 0xff) | ((q1 & 0xff) << 8) |
                             ((q2 & 0xff) << 16) | ((q3 & 0xff) << 24);
    }
}

// ---------------------------------------------------------------------------
// Kernel 3: int8 GEMM — 256x256 tile, template-faithful 2-buffer schedule.
// 512 thr = 8 waves (2M x 4N), wave tile 128x64, 16x16x64 i8 MFMA.
// Per K-tile: STAGE(t+1) issued FIRST (issue-early, vmcnt(0) only after all
// compute so HBM latency hides under the whole tile), then 2 phases of
// {ds_read -> s_barrier -> lgkmcnt(0) -> setprio(1) + 16 MFMA + setprio(0)},
// then vmcnt(0) + barrier. 2 LDS buffers (64KB), no modular indexing.
// Swizzle key (row>>1)&3 (proven 0-conflict in round 3), both-sides applied.
// ---------------------------------------------------------------------------
__global__ __launch_bounds__(512, 2)
void gemm_i8_kernel(const signed char* __restrict__ qx,   // [16384, 4096]
                    const signed char* __restrict__ qw,   // [4096, 4096]
                    const float* __restrict__ a_w,        // [4096]
                    const float* __restrict__ bias,       // [4096]
                    const float* __restrict__ axp,
                    float* __restrict__ out)              // [16384, 4096]
{
    __shared__ signed char As[2 * 256 * 64];   // 32 KB
    __shared__ signed char Bs[2 * 256 * 64];   // 32 KB

    const int tid  = threadIdx.x;
    const int lane = tid & 63;
    const int wid  = tid >> 6;     // 0..7
    const int wm   = wid >> 2;     // 0..1 (M half)
    const int wn   = wid & 3;      // 0..3 (N quarter)

    const int bid = blockIdx.x;
    const int nb  = bid & 15;      // same-nb blocks land on one XCD (bid%8 fixed)
    const int mb  = bid >> 4;

    const size_t K = DIN;
    constexpr int NT = DIN / 64;   // 64 K-tiles

    // ---- staging addressing: 512 thr x 16B = 8KB/pass, 2 passes/operand tile
    const int srow = tid >> 2;                              // 0..127 (pass adds 128)
    const int skb  = ((tid & 3) ^ ((srow >> 1) & 3)) << 4;  // inverse-swizzled src
    const signed char* aPanel = qx + (size_t)(mb * 256) * K;
    const signed char* bPanel = qw + (size_t)(nb * 256) * K;

    // ---- fragment read addressing (16x16x64: row=lane&15, K-block=lane>>4) ----
    const int r15  = lane & 15;
    const int blk  = lane >> 4;
    const int rkey = (r15 >> 1) & 3;                 // invariant across m/n (stride-16 rows)
    const int rblk = (blk ^ rkey) << 4;
    const int aRd  = (wm * 128 + r15) * 64 + rblk;   // + m*1024
    const int bRd  = (wn * 64 + r15) * 64 + rblk;    // + n*1024

    i32x4 acc[8][4];
    #pragma unroll
    for (int m = 0; m < 8; ++m)
        #pragma unroll
        for (int n = 0; n < 4; ++n) acc[m][n] = i32x4{0, 0, 0, 0};

    // stage one full K-tile (A and B) into buffer pb: 4 x global_load_lds(16B)
#define STAGE(tt, pb)                                                          \
    {                                                                          \
        const int tc = (tt) < NT ? (tt) : (NT - 1);                            \
        const size_t kOff = (size_t)tc * 64;                                   \
        _Pragma("unroll")                                                      \
        for (int j = 0; j < 2; ++j) {                                          \
            __builtin_amdgcn_global_load_lds(                                  \
                (const __attribute__((address_space(1))) unsigned int*)        \
                    (aPanel + (size_t)(j * 128 + srow) * K + kOff + skb),      \
                (__attribute__((address_space(3))) unsigned int*)              \
                    (As + (pb) * 16384 + j * 8192 + tid * 16),                 \
                16, 0, 0);                                                     \
        }                                                                      \
        _Pragma("unroll")                                                      \
        for (int j = 0; j < 2; ++j) {                                          \
            __builtin_amdgcn_global_load_lds(                                  \
                (const __attribute__((address_space(1))) unsigned int*)        \
                    (bPanel + (size_t)(j * 128 + srow) * K + kOff + skb),      \
                (__attribute__((address_space(3))) unsigned int*)              \
                    (Bs + (pb) * 16384 + j * 8192 + tid * 16),                 \
                16, 0, 0);                                                     \
        }                                                                      \
    }

    // ---- prologue: stage tile 0, wait, barrier ----
    STAGE(0, 0);
    asm volatile("s_waitcnt vmcnt(0)" ::: "memory");
    __builtin_amdgcn_sched_barrier(0);
    __builtin_amdgcn_s_barrier();

    for (int t = 0; t < NT; ++t) {
        const int p = t & 1;
        const signed char* Ab = As + p * 16384;
        const signed char* Bb = Bs + p * 16384;

        // issue next tile's loads FIRST — full K-tile of work hides the latency
        STAGE(t + 1, p ^ 1);

        // ---------- phase 0: read B n0-3 + A m0-3, MFMA upper half ----------
        i32x4 bf[4], af[4];
        #pragma unroll
        for (int n = 0; n < 4; ++n)
            bf[n] = *(const i32x4*)(Bb + bRd + n * 1024);
        #pragma unroll
        for (int m = 0; m < 4; ++m)
            af[m] = *(const i32x4*)(Ab + aRd + m * 1024);
        __builtin_amdgcn_s_barrier();
        asm volatile("s_waitcnt lgkmcnt(0)" ::: "memory");
        __builtin_amdgcn_sched_barrier(0);
        __builtin_amdgcn_s_setprio(1);
        #pragma unroll
        for (int m = 0; m < 4; ++m)
            #pragma unroll
            for (int n = 0; n < 4; ++n)
                acc[m][n] = __builtin_amdgcn_mfma_i32_16x16x64_i8(
                    af[m], bf[n], acc[m][n], 0, 0, 0);
        __builtin_amdgcn_s_setprio(0);
        __builtin_amdgcn_sched_barrier(0);

        // ---------- phase 1: read A m4-7 (B reused), MFMA lower half ----------
        i32x4 ag[4];
        #pragma unroll
        for (int m = 0; m < 4; ++m)
            ag[m] = *(const i32x4*)(Ab + aRd + (m + 4) * 1024);
        __builtin_amdgcn_s_barrier();
        asm volatile("s_waitcnt lgkmcnt(0)" ::: "memory");
        __builtin_amdgcn_sched_barrier(0);
        __builtin_amdgcn_s_setprio(1);
        #pragma unroll
        for (int m = 0; m < 4; ++m)
            #pragma unroll
            for (int n = 0; n < 4; ++n)
                acc[m + 4][n] = __builtin_amdgcn_mfma_i32_16x16x64_i8(
                    ag[m], bf[n], acc[m + 4][n], 0, 0, 0);
        __builtin_amdgcn_s_setprio(0);
        __builtin_amdgcn_sched_barrier(0);

        // ---------- tile end: next buffer must be resident ----------
        asm volatile("s_waitcnt vmcnt(0)" ::: "memory");
        __builtin_amdgcn_sched_barrier(0);
        __builtin_amdgcn_s_barrier();
    }
#undef STAGE

    // ---- epilogue: C/D layout col=lane&15, row=(lane>>4)*4+reg ----
    const float ax = fmaxf(axp[0], EPSF);
    #pragma unroll
    for (int n = 0; n < 4; ++n) {
        const int o = nb * 256 + wn * 64 + n * 16 + r15;
        const float scale = ax * a_w[o] * (1.0f / 16129.0f);
        const float bs = bias[o];
        #pragma unroll
        for (int m = 0; m < 8; ++m) {
            const int t0 = mb * 256 + wm * 128 + m * 16 + (blk << 2);
            float* op = out + (size_t)t0 * DOUT + o;
            #pragma unroll
            for (int r = 0; r < 4; ++r)
                op[(size_t)r * DOUT] = (float)acc[m][n][r] * scale + bs;
        }
    }
}

// ---------------------------------------------------------------------------
extern "C" void kernel_launch(void* const* d_in, const int* in_sizes, int n_in,
                              void* d_out, int out_size, void* d_ws, size_t ws_size,
                              hipStream_t stream)
{
    const float* x    = (const float*)d_in[0];
    const float* W    = (const float*)d_in[1];
    const float* lA   = (const float*)d_in[2];
    const float* lB   = (const float*)d_in[3];
    const float* bias = (const float*)d_in[4];
    const float* ax   = (const float*)d_in[5];
    float* out        = (float*)d_out;

    // workspace: qx (64MB) | qw (16MB) | a_w (16KB)
    signed char* qx = (signed char*)d_ws;
    signed char* qw = qx + (size_t)TDIM * DIN;
    float* a_w      = (float*)(qw + (size_t)DOUT * DIN);

    wquant_kernel<<<DOUT / 4, 256, 0, stream>>>(W, lA, lB, a_w, qw);

    const int xblocks = (int)(((size_t)TDIM * DIN) / (16 * 256));  // 16384
    xquant_kernel<<<xblocks, 256, 0, stream>>>(x, ax, (unsigned int*)qx);

    gemm_i8_kernel<<<(TDIM / 256) * (DOUT / 256), 512, 0, stream>>>(
        qx, qw, a_w, bias, ax, out);
}

// Round 5
// 462.473 us; speedup vs baseline: 1.1668x; 1.1668x over previous
//
#include <hip/hip_runtime.h>
#include <hip/hip_bf16.h>

// Problem constants (fixed by setup_inputs)
constexpr int TDIM = 16384;
constexpr int DIN  = 4096;
constexpr int DOUT = 4096;
constexpr int RNK  = 32;
constexpr float EPSF = 1e-8f;

using i32x4 = __attribute__((ext_vector_type(4))) int;

// ---------------------------------------------------------------------------
// Kernel 1: weight_eff = W + loraB @ loraA  -> per-row absmax -> int8 quantize
// (unchanged from round 2)
// ---------------------------------------------------------------------------
__global__ __launch_bounds__(256)
void wquant_kernel(const float* __restrict__ W,
                   const float* __restrict__ Amat,   // [32, 4096]
                   const float* __restrict__ Bmat,   // [4096, 32]
                   float* __restrict__ a_w,          // [4096]
                   signed char* __restrict__ qw)     // [4096, 4096]
{
    const int tid = threadIdx.x;
    const int o0  = blockIdx.x * 4;

    __shared__ float Bsh[4][32];
    __shared__ float red[4][4];
    __shared__ float awsh[4];

    if (tid < 128) {
        int r = tid >> 5, c = tid & 31;
        Bsh[r][c] = Bmat[(size_t)(o0 + r) * RNK + c];
    }
    __syncthreads();

    float4 acc[4][4];
    #pragma unroll
    for (int r = 0; r < 4; ++r)
        #pragma unroll
        for (int c = 0; c < 4; ++c)
            acc[r][c] = *(const float4*)(W + (size_t)(o0 + r) * DIN + c * 1024 + tid * 4);

    #pragma unroll 4
    for (int k = 0; k < RNK; ++k) {
        float4 a[4];
        #pragma unroll
        for (int c = 0; c < 4; ++c)
            a[c] = *(const float4*)(Amat + (size_t)k * DIN + c * 1024 + tid * 4);
        #pragma unroll
        for (int r = 0; r < 4; ++r) {
            const float b = Bsh[r][k];
            #pragma unroll
            for (int c = 0; c < 4; ++c) {
                acc[r][c].x += b * a[c].x; acc[r][c].y += b * a[c].y;
                acc[r][c].z += b * a[c].z; acc[r][c].w += b * a[c].w;
            }
        }
    }

    const int wid = tid >> 6;
    #pragma unroll
    for (int r = 0; r < 4; ++r) {
        float m = 0.f;
        #pragma unroll
        for (int c = 0; c < 4; ++c) {
            float4 v = acc[r][c];
            m = fmaxf(m, fmaxf(fmaxf(fabsf(v.x), fabsf(v.y)),
                               fmaxf(fabsf(v.z), fabsf(v.w))));
        }
        for (int off = 1; off < 64; off <<= 1)
            m = fmaxf(m, __shfl_xor(m, off));
        if ((tid & 63) == 0) red[wid][r] = m;
    }
    __syncthreads();
    if (tid < 4) {
        float m = fmaxf(fmaxf(red[0][tid], red[1][tid]),
                        fmaxf(red[2][tid], red[3][tid]));
        float aw = m + EPSF;
        awsh[tid] = aw;
        a_w[o0 + tid] = aw;
    }
    __syncthreads();

    #pragma unroll
    for (int r = 0; r < 4; ++r) {
        const float aw = awsh[r];
        #pragma unroll
        for (int c = 0; c < 4; ++c) {
            float4 v = acc[r][c];
            int q0 = __float2int_rn((v.x / aw) * 127.0f);
            int q1 = __float2int_rn((v.y / aw) * 127.0f);
            int q2 = __float2int_rn((v.z / aw) * 127.0f);
            int q3 = __float2int_rn((v.w / aw) * 127.0f);
            unsigned int packed = (q0 & 0xff) | ((q1 & 0xff) << 8) |
                                  ((q2 & 0xff) << 16) | ((q3 & 0xff) << 24);
            *(unsigned int*)(qw + (size_t)(o0 + r) * DIN + c * 1024 + tid * 4) = packed;
        }
    }
}

// ---------------------------------------------------------------------------
// Kernel 2: x quantize (unchanged from round 2 — coalesced)
// ---------------------------------------------------------------------------
__global__ __launch_bounds__(256)
void xquant_kernel(const float* __restrict__ x,
                   const float* __restrict__ axp,
                   unsigned int* __restrict__ qx)
{
    const float inv = 1.0f / fmaxf(axp[0], EPSF);
    const size_t base = (size_t)blockIdx.x * 1024 + threadIdx.x;
    const float4* xv = (const float4*)x;

    float4 v[4];
    #pragma unroll
    for (int j = 0; j < 4; ++j)
        v[j] = xv[base + j * 256];

    #pragma unroll
    for (int j = 0; j < 4; ++j) {
        int q0 = __float2int_rn(fminf(fmaxf(v[j].x * inv, -1.f), 1.f) * 127.0f);
        int q1 = __float2int_rn(fminf(fmaxf(v[j].y * inv, -1.f), 1.f) * 127.0f);
        int q2 = __float2int_rn(fminf(fmaxf(v[j].z * inv, -1.f), 1.f) * 127.0f);
        int q3 = __float2int_rn(fminf(fmaxf(v[j].w * inv, -1.f), 1.f) * 127.0f);
        qx[base + j * 256] = (q0 & 0xff) | ((q1 & 0xff) << 8) |
                             ((q2 & 0xff) << 16) | ((q3 & 0xff) << 24);
    }
}

// ---------------------------------------------------------------------------
// Kernel 3a: 8-phase 256x256 i8 GEMM, byte-isomorphic to the verified bf16
// template (m201): BK=128B, 2 dbuf x (A 32KB + B 32KB) = 128 KiB LDS,
// 8 waves (2Mx4N), wave tile 128x64, 4 phases/K-tile x {ds_read subtile,
// stage 1 half-tile (2x gload_lds), barrier, lgkmcnt(0), setprio+16 MFMA},
// counted vmcnt(4) once per K-tile. Handles M rows [0, mRows).
// Swizzle: 8x16B blocks per 128B row, key=(row>>1)&7, both-sides (rule #21).
// ---------------------------------------------------------------------------
__global__ __launch_bounds__(512, 2)
void gemm8_kernel(const signed char* __restrict__ qx,   // [16384, 4096]
                  const signed char* __restrict__ qw,   // [4096, 4096]
                  const float* __restrict__ a_w,
                  const float* __restrict__ bias,
                  const float* __restrict__ axp,
                  float* __restrict__ out)
{
    __shared__ signed char As[2 * 256 * 128];   // 64 KB
    __shared__ signed char Bs[2 * 256 * 128];   // 64 KB

    const int tid  = threadIdx.x;
    const int lane = tid & 63;
    const int wid  = tid >> 6;     // 0..7
    const int wm   = wid >> 2;     // 0..1 (M half of tile)
    const int wn   = wid & 3;      // 0..3 (N quarter)

    const int bid = blockIdx.x;
    const int nb  = bid & 15;
    const int mb  = bid >> 4;

    const size_t K = DIN;
    constexpr int NT = DIN / 128;  // 32 K-tiles of 128 bytes

    // ---- staging addressing: halftile = 128 rows x 128B = 16KB = 2 passes
    const int srow8 = tid >> 3;                       // 0..63 per pass
    const int sblk  = ((tid & 7) ^ ((tid >> 4) & 7)) << 4;  // pre-swizzled src block
    const signed char* aPanel = qx + (size_t)(mb * 256) * K;
    const signed char* bPanel = qw + (size_t)(nb * 256) * K;

    // ---- fragment read addressing (16x16x64: row=lane&15, 16B kblock=lane>>4)
    const int r15  = lane & 15;
    const int blk  = lane >> 4;
    const int key  = (r15 >> 1) & 7;
    const int sw0  = (blk ^ key) << 4;          // k-step 0 block byte
    const int sw1  = ((blk ^ key) ^ 4) << 4;    // k-step 1 block byte
    const int aRd0 = (wm * 128 + r15) * 128 + sw0;   // + mh*8192 + m*2048
    const int aRd1 = (wm * 128 + r15) * 128 + sw1;
    const int bRd0 = (wn * 64 + r15) * 128 + sw0;    // + n*2048
    const int bRd1 = (wn * 64 + r15) * 128 + sw1;

    i32x4 acc[8][4];
    #pragma unroll
    for (int m = 0; m < 8; ++m)
        #pragma unroll
        for (int n = 0; n < 4; ++n) acc[m][n] = i32x4{0, 0, 0, 0};

    // stage one half-tile (2 x global_load_lds 16B) of operand tile T into buf pb
#define STAGE_U(panel, ldsArr, T, h, pb)                                       \
    {                                                                          \
        const int tc = (T) < NT ? (T) : (NT - 1);                              \
        const size_t kOff = (size_t)tc * 128;                                  \
        _Pragma("unroll")                                                      \
        for (int j = 0; j < 2; ++j) {                                          \
            __builtin_amdgcn_global_load_lds(                                  \
                (const __attribute__((address_space(1))) unsigned int*)        \
                    ((panel) + (size_t)((h) * 128 + j * 64 + srow8) * K + kOff + sblk), \
                (__attribute__((address_space(3))) unsigned int*)              \
                    ((ldsArr) + (pb) * 32768 + (h) * 16384 + j * 8192 + tid * 16), \
                16, 0, 0);                                                     \
        }                                                                      \
    }

    // ---- prologue: queue = B(0)h0,h1  A(0)h0,h1  B(1)h0,h1 ; vmcnt(4) ----
    STAGE_U(bPanel, Bs, 0, 0, 0); STAGE_U(bPanel, Bs, 0, 1, 0);
    STAGE_U(aPanel, As, 0, 0, 0); STAGE_U(aPanel, As, 0, 1, 0);
    STAGE_U(bPanel, Bs, 1, 0, 1); STAGE_U(bPanel, Bs, 1, 1, 1);
    asm volatile("s_waitcnt vmcnt(4)" ::: "memory");
    __builtin_amdgcn_sched_barrier(0);
    __builtin_amdgcn_s_barrier();

    for (int t = 0; t < NT; ++t) {
        const int p = t & 1;
        const signed char* Ab = As + p * 32768;
        const signed char* Bb = Bs + p * 32768;
        i32x4 bf0[4], bf1[4], af[4];

        // ---- phase 0: (mh0, k0) — read bf0 + af; stage A(t+1) h0 -> buf p^1
        #pragma unroll
        for (int n = 0; n < 4; ++n) bf0[n] = *(const i32x4*)(Bb + bRd0 + n * 2048);
        #pragma unroll
        for (int m = 0; m < 4; ++m) af[m] = *(const i32x4*)(Ab + aRd0 + m * 2048);
        STAGE_U(aPanel, As, t + 1, 0, p ^ 1);
        __builtin_amdgcn_s_barrier();
        asm volatile("s_waitcnt lgkmcnt(0)" ::: "memory");
        __builtin_amdgcn_sched_barrier(0);
        __builtin_amdgcn_s_setprio(1);
        #pragma unroll
        for (int m = 0; m < 4; ++m)
            #pragma unroll
            for (int n = 0; n < 4; ++n)
                acc[m][n] = __builtin_amdgcn_mfma_i32_16x16x64_i8(af[m], bf0[n], acc[m][n], 0, 0, 0);
        __builtin_amdgcn_s_setprio(0);
        __builtin_amdgcn_sched_barrier(0);
        __builtin_amdgcn_s_barrier();

        // ---- phase 1: (mh0, k1) — read bf1 + af; stage A(t+1) h1 -> buf p^1
        #pragma unroll
        for (int n = 0; n < 4; ++n) bf1[n] = *(const i32x4*)(Bb + bRd1 + n * 2048);
        #pragma unroll
        for (int m = 0; m < 4; ++m) af[m] = *(const i32x4*)(Ab + aRd1 + m * 2048);
        STAGE_U(aPanel, As, t + 1, 1, p ^ 1);
        __builtin_amdgcn_s_barrier();
        asm volatile("s_waitcnt lgkmcnt(0)" ::: "memory");
        __builtin_amdgcn_sched_barrier(0);
        __builtin_amdgcn_s_setprio(1);
        #pragma unroll
        for (int m = 0; m < 4; ++m)
            #pragma unroll
            for (int n = 0; n < 4; ++n)
                acc[m][n] = __builtin_amdgcn_mfma_i32_16x16x64_i8(af[m], bf1[n], acc[m][n], 0, 0, 0);
        __builtin_amdgcn_s_setprio(0);
        __builtin_amdgcn_sched_barrier(0);
        __builtin_amdgcn_s_barrier();

        // ---- phase 2: (mh1, k0) — read af (bf0 reused); stage B(t+2) h0 -> buf p
        #pragma unroll
        for (int m = 0; m < 4; ++m) af[m] = *(const i32x4*)(Ab + aRd0 + 8192 + m * 2048);
        STAGE_U(bPanel, Bs, t + 2, 0, p);
        __builtin_amdgcn_s_barrier();
        asm volatile("s_waitcnt lgkmcnt(0)" ::: "memory");
        __builtin_amdgcn_sched_barrier(0);
        __builtin_amdgcn_s_setprio(1);
        #pragma unroll
        for (int m = 0; m < 4; ++m)
            #pragma unroll
            for (int n = 0; n < 4; ++n)
                acc[m + 4][n] = __builtin_amdgcn_mfma_i32_16x16x64_i8(af[m], bf0[n], acc[m + 4][n], 0, 0, 0);
        __builtin_amdgcn_s_setprio(0);
        __builtin_amdgcn_sched_barrier(0);
        __builtin_amdgcn_s_barrier();

        // ---- phase 3: (mh1, k1) — read af (bf1 reused); stage B(t+2) h1 -> buf p
        #pragma unroll
        for (int m = 0; m < 4; ++m) af[m] = *(const i32x4*)(Ab + aRd1 + 8192 + m * 2048);
        STAGE_U(bPanel, Bs, t + 2, 1, p);
        __builtin_amdgcn_s_barrier();
        asm volatile("s_waitcnt lgkmcnt(0)" ::: "memory");
        __builtin_amdgcn_sched_barrier(0);
        __builtin_amdgcn_s_setprio(1);
        #pragma unroll
        for (int m = 0; m < 4; ++m)
            #pragma unroll
            for (int n = 0; n < 4; ++n)
                acc[m + 4][n] = __builtin_amdgcn_mfma_i32_16x16x64_i8(af[m], bf1[n], acc[m + 4][n], 0, 0, 0);
        __builtin_amdgcn_s_setprio(0);
        __builtin_amdgcn_sched_barrier(0);
        // counted vmcnt ONCE per K-tile: retire tile t+1's 4 units, float B(t+2)
        asm volatile("s_waitcnt vmcnt(4)" ::: "memory");
        __builtin_amdgcn_sched_barrier(0);
        __builtin_amdgcn_s_barrier();
    }
#undef STAGE_U

    // drain dangling tail dummy-stages before LDS is freed
    asm volatile("s_waitcnt vmcnt(0)" ::: "memory");

    // ---- epilogue: C/D layout col=lane&15, row=(lane>>4)*4+reg ----
    const float ax = fmaxf(axp[0], EPSF);
    #pragma unroll
    for (int n = 0; n < 4; ++n) {
        const int o = nb * 256 + wn * 64 + n * 16 + r15;
        const float scale = ax * a_w[o] * (1.0f / 16129.0f);
        const float bs = bias[o];
        #pragma unroll
        for (int m = 0; m < 8; ++m) {
            const int t0 = mb * 256 + wm * 128 + m * 16 + (blk << 2);
            float* op = out + (size_t)t0 * DOUT + o;
            #pragma unroll
            for (int r = 0; r < 4; ++r)
                op[(size_t)r * DOUT] = (float)acc[m][n][r] * scale + bs;
        }
    }
}

// ---------------------------------------------------------------------------
// Kernel 3b: round-2 m97-structure 128x128 GEMM (proven 349us full-M rate),
// covering rows [mBase, mBase + 128*gridM). A/B comparator + fallback.
// ---------------------------------------------------------------------------
__global__ __launch_bounds__(256, 2)
void gemm97_kernel(const signed char* __restrict__ qx,
                   const signed char* __restrict__ qw,
                   const float* __restrict__ a_w,
                   const float* __restrict__ bias,
                   const float* __restrict__ axp,
                   float* __restrict__ out,
                   int mBase)
{
    __shared__ signed char As[128 * 64];
    __shared__ signed char Bs[128 * 64];

    const int tid  = threadIdx.x;
    const int lane = tid & 63;
    const int wid  = tid >> 6;
    const int wm   = wid >> 1;
    const int wn   = wid & 1;

    const int bid = blockIdx.x;
    const int nb  = bid & 31;
    const int mb  = bid >> 5;

    const size_t K = DIN;

    const int srow = tid >> 2;
    const int skb  = tid & 3;
    const int ssw  = (srow ^ (srow >> 2)) & 3;
    const int skb2 = skb ^ ssw;

    const signed char* aSrc = qx + (size_t)(mBase + mb * 128) * K;
    const signed char* bSrc = qw + (size_t)(nb * 128) * K;

    const int r15 = lane & 15;
    const int rsw = (r15 ^ (r15 >> 2)) & 3;
    const int rkb = (((lane >> 4) ^ rsw) << 4);
    const int aRdBase = (wm * 64 + r15) * 64 + rkb;
    const int bRdBase = (wn * 64 + r15) * 64 + rkb;

    i32x4 acc[4][4];
    #pragma unroll
    for (int m = 0; m < 4; ++m)
        #pragma unroll
        for (int n = 0; n < 4; ++n) acc[m][n] = i32x4{0, 0, 0, 0};

    for (int kt = 0; kt < (int)(K / 64); ++kt) {
        const size_t kOff = (size_t)kt * 64;
        #pragma unroll
        for (int j = 0; j < 2; ++j) {
            const int row = j * 64 + srow;
            __builtin_amdgcn_global_load_lds(
                (const __attribute__((address_space(1))) unsigned int*)
                    (aSrc + (size_t)row * K + kOff + skb2 * 16),
                (__attribute__((address_space(3))) unsigned int*)
                    (As + j * 4096 + tid * 16),
                16, 0, 0);
        }
        #pragma unroll
        for (int j = 0; j < 2; ++j) {
            const int row = j * 64 + srow;
            __builtin_amdgcn_global_load_lds(
                (const __attribute__((address_space(1))) unsigned int*)
                    (bSrc + (size_t)row * K + kOff + skb2 * 16),
                (__attribute__((address_space(3))) unsigned int*)
                    (Bs + j * 4096 + tid * 16),
                16, 0, 0);
        }
        __syncthreads();

        i32x4 af[4], bf[4];
        #pragma unroll
        for (int m = 0; m < 4; ++m)
            af[m] = *(const i32x4*)(As + aRdBase + m * 1024);
        #pragma unroll
        for (int n = 0; n < 4; ++n)
            bf[n] = *(const i32x4*)(Bs + bRdBase + n * 1024);

        #pragma unroll
        for (int m = 0; m < 4; ++m)
            #pragma unroll
            for (int n = 0; n < 4; ++n)
                acc[m][n] = __builtin_amdgcn_mfma_i32_16x16x64_i8(
                    af[m], bf[n], acc[m][n], 0, 0, 0);

        __syncthreads();
    }

    const float ax = fmaxf(axp[0], EPSF);
    #pragma unroll
    for (int n = 0; n < 4; ++n) {
        const int o = nb * 128 + wn * 64 + n * 16 + r15;
        const float scale = ax * a_w[o] * (1.0f / 16129.0f);
        const float bs = bias[o];
        #pragma unroll
        for (int m = 0; m < 4; ++m) {
            const int t0 = mBase + mb * 128 + wm * 64 + m * 16 + ((lane >> 4) << 2);
            float* op = out + (size_t)t0 * DOUT + o;
            #pragma unroll
            for (int r = 0; r < 4; ++r)
                op[(size_t)r * DOUT] = (float)acc[m][n][r] * scale + bs;
        }
    }
}

// ---------------------------------------------------------------------------
extern "C" void kernel_launch(void* const* d_in, const int* in_sizes, int n_in,
                              void* d_out, int out_size, void* d_ws, size_t ws_size,
                              hipStream_t stream)
{
    const float* x    = (const float*)d_in[0];
    const float* W    = (const float*)d_in[1];
    const float* lA   = (const float*)d_in[2];
    const float* lB   = (const float*)d_in[3];
    const float* bias = (const float*)d_in[4];
    const float* ax   = (const float*)d_in[5];
    float* out        = (float*)d_out;

    // workspace: qx (64MB) | qw (16MB) | a_w (16KB)
    signed char* qx = (signed char*)d_ws;
    signed char* qw = qx + (size_t)TDIM * DIN;
    float* a_w      = (float*)(qw + (size_t)DOUT * DIN);

    wquant_kernel<<<DOUT / 4, 256, 0, stream>>>(W, lA, lB, a_w, qw);

    const int xblocks = (int)(((size_t)TDIM * DIN) / (16 * 256));  // 16384
    xquant_kernel<<<xblocks, 256, 0, stream>>>(x, ax, (unsigned int*)qx);

    // A/B split: rows [0, 8192) via 8-phase template, rows [8192, 16384) via
    // proven m97 structure. rocprof reports the two dispatches separately.
    gemm8_kernel<<<(8192 / 256) * (DOUT / 256), 512, 0, stream>>>(
        qx, qw, a_w, bias, ax, out);
    gemm97_kernel<<<(8192 / 128) * (DOUT / 128), 256, 0, stream>>>(
        qx, qw, a_w, bias, ax, out, 8192);
}

// Round 6
// 415.245 us; speedup vs baseline: 1.2995x; 1.1137x over previous
//
#include <hip/hip_runtime.h>
#include <hip/hip_bf16.h>

// Problem constants (fixed by setup_inputs)
constexpr int TDIM = 16384;
constexpr int DIN  = 4096;
constexpr int DOUT = 4096;
constexpr int RNK  = 32;
constexpr float EPSF = 1e-8f;

using i32x4 = __attribute__((ext_vector_type(4))) int;

// ---------------------------------------------------------------------------
// Kernel 1: weight_eff = W + loraB @ loraA  -> per-row absmax -> int8 quantize
// (unchanged from round 2)
// ---------------------------------------------------------------------------
__global__ __launch_bounds__(256)
void wquant_kernel(const float* __restrict__ W,
                   const float* __restrict__ Amat,   // [32, 4096]
                   const float* __restrict__ Bmat,   // [4096, 32]
                   float* __restrict__ a_w,          // [4096]
                   signed char* __restrict__ qw)     // [4096, 4096]
{
    const int tid = threadIdx.x;
    const int o0  = blockIdx.x * 4;

    __shared__ float Bsh[4][32];
    __shared__ float red[4][4];
    __shared__ float awsh[4];

    if (tid < 128) {
        int r = tid >> 5, c = tid & 31;
        Bsh[r][c] = Bmat[(size_t)(o0 + r) * RNK + c];
    }
    __syncthreads();

    float4 acc[4][4];
    #pragma unroll
    for (int r = 0; r < 4; ++r)
        #pragma unroll
        for (int c = 0; c < 4; ++c)
            acc[r][c] = *(const float4*)(W + (size_t)(o0 + r) * DIN + c * 1024 + tid * 4);

    #pragma unroll 4
    for (int k = 0; k < RNK; ++k) {
        float4 a[4];
        #pragma unroll
        for (int c = 0; c < 4; ++c)
            a[c] = *(const float4*)(Amat + (size_t)k * DIN + c * 1024 + tid * 4);
        #pragma unroll
        for (int r = 0; r < 4; ++r) {
            const float b = Bsh[r][k];
            #pragma unroll
            for (int c = 0; c < 4; ++c) {
                acc[r][c].x += b * a[c].x; acc[r][c].y += b * a[c].y;
                acc[r][c].z += b * a[c].z; acc[r][c].w += b * a[c].w;
            }
        }
    }

    const int wid = tid >> 6;
    #pragma unroll
    for (int r = 0; r < 4; ++r) {
        float m = 0.f;
        #pragma unroll
        for (int c = 0; c < 4; ++c) {
            float4 v = acc[r][c];
            m = fmaxf(m, fmaxf(fmaxf(fabsf(v.x), fabsf(v.y)),
                               fmaxf(fabsf(v.z), fabsf(v.w))));
        }
        for (int off = 1; off < 64; off <<= 1)
            m = fmaxf(m, __shfl_xor(m, off));
        if ((tid & 63) == 0) red[wid][r] = m;
    }
    __syncthreads();
    if (tid < 4) {
        float m = fmaxf(fmaxf(red[0][tid], red[1][tid]),
                        fmaxf(red[2][tid], red[3][tid]));
        float aw = m + EPSF;
        awsh[tid] = aw;
        a_w[o0 + tid] = aw;
    }
    __syncthreads();

    #pragma unroll
    for (int r = 0; r < 4; ++r) {
        const float aw = awsh[r];
        #pragma unroll
        for (int c = 0; c < 4; ++c) {
            float4 v = acc[r][c];
            int q0 = __float2int_rn((v.x / aw) * 127.0f);
            int q1 = __float2int_rn((v.y / aw) * 127.0f);
            int q2 = __float2int_rn((v.z / aw) * 127.0f);
            int q3 = __float2int_rn((v.w / aw) * 127.0f);
            unsigned int packed = (q0 & 0xff) | ((q1 & 0xff) << 8) |
                                  ((q2 & 0xff) << 16) | ((q3 & 0xff) << 24);
            *(unsigned int*)(qw + (size_t)(o0 + r) * DIN + c * 1024 + tid * 4) = packed;
        }
    }
}

// ---------------------------------------------------------------------------
// Kernel 2: x quantize (unchanged from round 2 — coalesced)
// ---------------------------------------------------------------------------
__global__ __launch_bounds__(256)
void xquant_kernel(const float* __restrict__ x,
                   const float* __restrict__ axp,
                   unsigned int* __restrict__ qx)
{
    const float inv = 1.0f / fmaxf(axp[0], EPSF);
    const size_t base = (size_t)blockIdx.x * 1024 + threadIdx.x;
    const float4* xv = (const float4*)x;

    float4 v[4];
    #pragma unroll
    for (int j = 0; j < 4; ++j)
        v[j] = xv[base + j * 256];

    #pragma unroll
    for (int j = 0; j < 4; ++j) {
        int q0 = __float2int_rn(fminf(fmaxf(v[j].x * inv, -1.f), 1.f) * 127.0f);
        int q1 = __float2int_rn(fminf(fmaxf(v[j].y * inv, -1.f), 1.f) * 127.0f);
        int q2 = __float2int_rn(fminf(fmaxf(v[j].z * inv, -1.f), 1.f) * 127.0f);
        int q3 = __float2int_rn(fminf(fmaxf(v[j].w * inv, -1.f), 1.f) * 127.0f);
        qx[base + j * 256] = (q0 & 0xff) | ((q1 & 0xff) << 8) |
                             ((q2 & 0xff) << 16) | ((q3 & 0xff) << 24);
    }
}

// ---------------------------------------------------------------------------
// Kernel 3: 8-phase 256x256 i8 GEMM (full M), BK=128B, 2 dbuf (128 KiB LDS),
// 8 waves (2Mx4N), wave tile 128x64.  NEW vs round 5: A-frags for phases 2-3
// (af2/af3) are prefetched during phases 0-1 with counted lgkmcnt(4) waits
// (order pinned by sched_barrier), so phases 2-3 have no exposed LDS wait and
// their ds_read time drains under phases 0-1's MFMA clusters.
// vmcnt bookkeeping (loads): tile-start pending = B(t+1)x4; tile issues
// A(t+1)x4 + B(t+2)x4 -> 12; end-of-tile vmcnt(4) retires B(t+1)+A(t+1). ✓
// ---------------------------------------------------------------------------
__global__ __launch_bounds__(512, 2)
void gemm8_kernel(const signed char* __restrict__ qx,   // [16384, 4096]
                  const signed char* __restrict__ qw,   // [4096, 4096]
                  const float* __restrict__ a_w,
                  const float* __restrict__ bias,
                  const float* __restrict__ axp,
                  float* __restrict__ out)
{
    __shared__ signed char As[2 * 256 * 128];   // 64 KB
    __shared__ signed char Bs[2 * 256 * 128];   // 64 KB

    const int tid  = threadIdx.x;
    const int lane = tid & 63;
    const int wid  = tid >> 6;     // 0..7
    const int wm   = wid >> 2;     // 0..1 (M half of tile)
    const int wn   = wid & 3;      // 0..3 (N quarter)

    const int bid = blockIdx.x;
    const int nb  = bid & 15;
    const int mb  = bid >> 4;

    const size_t K = DIN;
    constexpr int NT = DIN / 128;  // 32 K-tiles of 128 bytes

    // ---- staging addressing: halftile = 128 rows x 128B = 16KB = 2 passes
    const int srow8 = tid >> 3;                             // 0..63 per pass
    const int sblk  = ((tid & 7) ^ ((tid >> 4) & 7)) << 4;  // pre-swizzled src block
    const signed char* aPanel = qx + (size_t)(mb * 256) * K;
    const signed char* bPanel = qw + (size_t)(nb * 256) * K;

    // ---- fragment read addressing (16x16x64: row=lane&15, 16B kblock=lane>>4)
    const int r15  = lane & 15;
    const int blk  = lane >> 4;
    const int key  = (r15 >> 1) & 7;
    const int sw0  = (blk ^ key) << 4;          // k-step 0 block byte
    const int sw1  = ((blk ^ key) ^ 4) << 4;    // k-step 1 block byte
    const int aRd0 = (wm * 128 + r15) * 128 + sw0;   // + mh*8192 + m*2048
    const int aRd1 = (wm * 128 + r15) * 128 + sw1;
    const int bRd0 = (wn * 64 + r15) * 128 + sw0;    // + n*2048
    const int bRd1 = (wn * 64 + r15) * 128 + sw1;

    i32x4 acc[8][4];
    #pragma unroll
    for (int m = 0; m < 8; ++m)
        #pragma unroll
        for (int n = 0; n < 4; ++n) acc[m][n] = i32x4{0, 0, 0, 0};

    // stage one half-tile (2 x global_load_lds 16B) of operand tile T into buf pb
#define STAGE_U(panel, ldsArr, T, h, pb)                                       \
    {                                                                          \
        const int tc = (T) < NT ? (T) : (NT - 1);                              \
        const size_t kOff = (size_t)tc * 128;                                  \
        _Pragma("unroll")                                                      \
        for (int j = 0; j < 2; ++j) {                                          \
            __builtin_amdgcn_global_load_lds(                                  \
                (const __attribute__((address_space(1))) unsigned int*)        \
                    ((panel) + (size_t)((h) * 128 + j * 64 + srow8) * K + kOff + sblk), \
                (__attribute__((address_space(3))) unsigned int*)              \
                    ((ldsArr) + (pb) * 32768 + (h) * 16384 + j * 8192 + tid * 16), \
                16, 0, 0);                                                     \
        }                                                                      \
    }

    // ---- prologue: queue = B(0)h0,h1  A(0)h0,h1  B(1)h0,h1 (12 loads);
    //      vmcnt(4) retires 8 = all of B(0), A(0). ----
    STAGE_U(bPanel, Bs, 0, 0, 0); STAGE_U(bPanel, Bs, 0, 1, 0);
    STAGE_U(aPanel, As, 0, 0, 0); STAGE_U(aPanel, As, 0, 1, 0);
    STAGE_U(bPanel, Bs, 1, 0, 1); STAGE_U(bPanel, Bs, 1, 1, 1);
    asm volatile("s_waitcnt vmcnt(4)" ::: "memory");
    __builtin_amdgcn_sched_barrier(0);
    __builtin_amdgcn_s_barrier();

    for (int t = 0; t < NT; ++t) {
        const int p = t & 1;
        const signed char* Ab = As + p * 32768;
        const signed char* Bb = Bs + p * 32768;
        i32x4 bf0[4], bf1[4], af0[4], af1[4], af2[4], af3[4];

        // ---- phase 0: (mh0,k0) reads + prefetch af2 (mh1,k0); stage A(t+1)h0
        #pragma unroll
        for (int n = 0; n < 4; ++n) bf0[n] = *(const i32x4*)(Bb + bRd0 + n * 2048);
        #pragma unroll
        for (int m = 0; m < 4; ++m) af0[m] = *(const i32x4*)(Ab + aRd0 + m * 2048);
        __builtin_amdgcn_sched_barrier(0);   // pin: bf0/af0 issue before af2
        #pragma unroll
        for (int m = 0; m < 4; ++m) af2[m] = *(const i32x4*)(Ab + aRd0 + 8192 + m * 2048);
        STAGE_U(aPanel, As, t + 1, 0, p ^ 1);
        __builtin_amdgcn_s_barrier();
        asm volatile("s_waitcnt lgkmcnt(4)" ::: "memory");  // bf0+af0 done, af2 may pend
        __builtin_amdgcn_sched_barrier(0);
        __builtin_amdgcn_s_setprio(1);
        #pragma unroll
        for (int m = 0; m < 4; ++m)
            #pragma unroll
            for (int n = 0; n < 4; ++n)
                acc[m][n] = __builtin_amdgcn_mfma_i32_16x16x64_i8(af0[m], bf0[n], acc[m][n], 0, 0, 0);
        __builtin_amdgcn_s_setprio(0);
        __builtin_amdgcn_sched_barrier(0);
        __builtin_amdgcn_s_barrier();

        // ---- phase 1: (mh0,k1) reads + prefetch af3 (mh1,k1); stage A(t+1)h1
        #pragma unroll
        for (int n = 0; n < 4; ++n) bf1[n] = *(const i32x4*)(Bb + bRd1 + n * 2048);
        #pragma unroll
        for (int m = 0; m < 4; ++m) af1[m] = *(const i32x4*)(Ab + aRd1 + m * 2048);
        __builtin_amdgcn_sched_barrier(0);   // pin: bf1/af1 issue before af3
        #pragma unroll
        for (int m = 0; m < 4; ++m) af3[m] = *(const i32x4*)(Ab + aRd1 + 8192 + m * 2048);
        STAGE_U(aPanel, As, t + 1, 1, p ^ 1);
        __builtin_amdgcn_s_barrier();
        asm volatile("s_waitcnt lgkmcnt(4)" ::: "memory");  // af2,bf1,af1 done; af3 may pend
        __builtin_amdgcn_sched_barrier(0);
        __builtin_amdgcn_s_setprio(1);
        #pragma unroll
        for (int m = 0; m < 4; ++m)
            #pragma unroll
            for (int n = 0; n < 4; ++n)
                acc[m][n] = __builtin_amdgcn_mfma_i32_16x16x64_i8(af1[m], bf1[n], acc[m][n], 0, 0, 0);
        __builtin_amdgcn_s_setprio(0);
        __builtin_amdgcn_sched_barrier(0);
        __builtin_amdgcn_s_barrier();

        // ---- phase 2: (mh1,k0) — af2/bf0 already in regs; stage B(t+2)h0
        STAGE_U(bPanel, Bs, t + 2, 0, p);
        __builtin_amdgcn_s_barrier();
        asm volatile("s_waitcnt lgkmcnt(4)" ::: "memory");  // af2 done (af3 may pend)
        __builtin_amdgcn_sched_barrier(0);
        __builtin_amdgcn_s_setprio(1);
        #pragma unroll
        for (int m = 0; m < 4; ++m)
            #pragma unroll
            for (int n = 0; n < 4; ++n)
                acc[m + 4][n] = __builtin_amdgcn_mfma_i32_16x16x64_i8(af2[m], bf0[n], acc[m + 4][n], 0, 0, 0);
        __builtin_amdgcn_s_setprio(0);
        __builtin_amdgcn_sched_barrier(0);
        __builtin_amdgcn_s_barrier();

        // ---- phase 3: (mh1,k1) — af3/bf1 already in regs; stage B(t+2)h1
        STAGE_U(bPanel, Bs, t + 2, 1, p);
        __builtin_amdgcn_s_barrier();
        asm volatile("s_waitcnt lgkmcnt(0)" ::: "memory");  // drain af3
        __builtin_amdgcn_sched_barrier(0);
        __builtin_amdgcn_s_setprio(1);
        #pragma unroll
        for (int m = 0; m < 4; ++m)
            #pragma unroll
            for (int n = 0; n < 4; ++n)
                acc[m + 4][n] = __builtin_amdgcn_mfma_i32_16x16x64_i8(af3[m], bf1[n], acc[m + 4][n], 0, 0, 0);
        __builtin_amdgcn_s_setprio(0);
        __builtin_amdgcn_sched_barrier(0);
        // counted vmcnt ONCE per K-tile: retires B(t+1)+A(t+1), floats B(t+2)
        asm volatile("s_waitcnt vmcnt(4)" ::: "memory");
        __builtin_amdgcn_sched_barrier(0);
        __builtin_amdgcn_s_barrier();
    }
#undef STAGE_U

    // drain dangling tail dummy-stages before epilogue
    asm volatile("s_waitcnt vmcnt(0)" ::: "memory");

    // ---- epilogue: C/D layout col=lane&15, row=(lane>>4)*4+reg ----
    const float ax = fmaxf(axp[0], EPSF);
    #pragma unroll
    for (int n = 0; n < 4; ++n) {
        const int o = nb * 256 + wn * 64 + n * 16 + r15;
        const float scale = ax * a_w[o] * (1.0f / 16129.0f);
        const float bs = bias[o];
        #pragma unroll
        for (int m = 0; m < 8; ++m) {
            const int t0 = mb * 256 + wm * 128 + m * 16 + (blk << 2);
            float* op = out + (size_t)t0 * DOUT + o;
            #pragma unroll
            for (int r = 0; r < 4; ++r)
                op[(size_t)r * DOUT] = (float)acc[m][n][r] * scale + bs;
        }
    }
}

// ---------------------------------------------------------------------------
extern "C" void kernel_launch(void* const* d_in, const int* in_sizes, int n_in,
                              void* d_out, int out_size, void* d_ws, size_t ws_size,
                              hipStream_t stream)
{
    const float* x    = (const float*)d_in[0];
    const float* W    = (const float*)d_in[1];
    const float* lA   = (const float*)d_in[2];
    const float* lB   = (const float*)d_in[3];
    const float* bias = (const float*)d_in[4];
    const float* ax   = (const float*)d_in[5];
    float* out        = (float*)d_out;

    // workspace: qx (64MB) | qw (16MB) | a_w (16KB)
    signed char* qx = (signed char*)d_ws;
    signed char* qw = qx + (size_t)TDIM * DIN;
    float* a_w      = (float*)(qw + (size_t)DOUT * DIN);

    wquant_kernel<<<DOUT / 4, 256, 0, stream>>>(W, lA, lB, a_w, qw);

    const int xblocks = (int)(((size_t)TDIM * DIN) / (16 * 256));  // 16384
    xquant_kernel<<<xblocks, 256, 0, stream>>>(x, ax, (unsigned int*)qx);

    gemm8_kernel<<<(TDIM / 256) * (DOUT / 256), 512, 0, stream>>>(
        qx, qw, a_w, bias, ax, out);
}

// Round 7
// 409.831 us; speedup vs baseline: 1.3167x; 1.0132x over previous
//
#include <hip/hip_runtime.h>
#include <hip/hip_bf16.h>

// Problem constants (fixed by setup_inputs)
constexpr int TDIM = 16384;
constexpr int DIN  = 4096;
constexpr int DOUT = 4096;
constexpr int RNK  = 32;
constexpr float EPSF = 1e-8f;

using i32x4 = __attribute__((ext_vector_type(4))) int;

// ---------------------------------------------------------------------------
// Kernel 1: weight_eff = W + loraB @ loraA  -> per-row absmax -> int8 quantize
// (unchanged from round 2)
// ---------------------------------------------------------------------------
__global__ __launch_bounds__(256)
void wquant_kernel(const float* __restrict__ W,
                   const float* __restrict__ Amat,   // [32, 4096]
                   const float* __restrict__ Bmat,   // [4096, 32]
                   float* __restrict__ a_w,          // [4096]
                   signed char* __restrict__ qw)     // [4096, 4096]
{
    const int tid = threadIdx.x;
    const int o0  = blockIdx.x * 4;

    __shared__ float Bsh[4][32];
    __shared__ float red[4][4];
    __shared__ float awsh[4];

    if (tid < 128) {
        int r = tid >> 5, c = tid & 31;
        Bsh[r][c] = Bmat[(size_t)(o0 + r) * RNK + c];
    }
    __syncthreads();

    float4 acc[4][4];
    #pragma unroll
    for (int r = 0; r < 4; ++r)
        #pragma unroll
        for (int c = 0; c < 4; ++c)
            acc[r][c] = *(const float4*)(W + (size_t)(o0 + r) * DIN + c * 1024 + tid * 4);

    #pragma unroll 4
    for (int k = 0; k < RNK; ++k) {
        float4 a[4];
        #pragma unroll
        for (int c = 0; c < 4; ++c)
            a[c] = *(const float4*)(Amat + (size_t)k * DIN + c * 1024 + tid * 4);
        #pragma unroll
        for (int r = 0; r < 4; ++r) {
            const float b = Bsh[r][k];
            #pragma unroll
            for (int c = 0; c < 4; ++c) {
                acc[r][c].x += b * a[c].x; acc[r][c].y += b * a[c].y;
                acc[r][c].z += b * a[c].z; acc[r][c].w += b * a[c].w;
            }
        }
    }

    const int wid = tid >> 6;
    #pragma unroll
    for (int r = 0; r < 4; ++r) {
        float m = 0.f;
        #pragma unroll
        for (int c = 0; c < 4; ++c) {
            float4 v = acc[r][c];
            m = fmaxf(m, fmaxf(fmaxf(fabsf(v.x), fabsf(v.y)),
                               fmaxf(fabsf(v.z), fabsf(v.w))));
        }
        for (int off = 1; off < 64; off <<= 1)
            m = fmaxf(m, __shfl_xor(m, off));
        if ((tid & 63) == 0) red[wid][r] = m;
    }
    __syncthreads();
    if (tid < 4) {
        float m = fmaxf(fmaxf(red[0][tid], red[1][tid]),
                        fmaxf(red[2][tid], red[3][tid]));
        float aw = m + EPSF;
        awsh[tid] = aw;
        a_w[o0 + tid] = aw;
    }
    __syncthreads();

    #pragma unroll
    for (int r = 0; r < 4; ++r) {
        const float aw = awsh[r];
        #pragma unroll
        for (int c = 0; c < 4; ++c) {
            float4 v = acc[r][c];
            int q0 = __float2int_rn((v.x / aw) * 127.0f);
            int q1 = __float2int_rn((v.y / aw) * 127.0f);
            int q2 = __float2int_rn((v.z / aw) * 127.0f);
            int q3 = __float2int_rn((v.w / aw) * 127.0f);
            unsigned int packed = (q0 & 0xff) | ((q1 & 0xff) << 8) |
                                  ((q2 & 0xff) << 16) | ((q3 & 0xff) << 24);
            *(unsigned int*)(qw + (size_t)(o0 + r) * DIN + c * 1024 + tid * 4) = packed;
        }
    }
}

// ---------------------------------------------------------------------------
// Kernel 2: x quantize (unchanged from round 2 — coalesced)
// ---------------------------------------------------------------------------
__global__ __launch_bounds__(256)
void xquant_kernel(const float* __restrict__ x,
                   const float* __restrict__ axp,
                   unsigned int* __restrict__ qx)
{
    const float inv = 1.0f / fmaxf(axp[0], EPSF);
    const size_t base = (size_t)blockIdx.x * 1024 + threadIdx.x;
    const float4* xv = (const float4*)x;

    float4 v[4];
    #pragma unroll
    for (int j = 0; j < 4; ++j)
        v[j] = xv[base + j * 256];

    #pragma unroll
    for (int j = 0; j < 4; ++j) {
        int q0 = __float2int_rn(fminf(fmaxf(v[j].x * inv, -1.f), 1.f) * 127.0f);
        int q1 = __float2int_rn(fminf(fmaxf(v[j].y * inv, -1.f), 1.f) * 127.0f);
        int q2 = __float2int_rn(fminf(fmaxf(v[j].z * inv, -1.f), 1.f) * 127.0f);
        int q3 = __float2int_rn(fminf(fmaxf(v[j].w * inv, -1.f), 1.f) * 127.0f);
        qx[base + j * 256] = (q0 & 0xff) | ((q1 & 0xff) << 8) |
                             ((q2 & 0xff) << 16) | ((q3 & 0xff) << 24);
    }
}

// ---------------------------------------------------------------------------
// Shared GEMM geometry (256x256 tile, BK=128B, 8 waves 2Mx4N, 2 dbuf 128KiB)
// ---------------------------------------------------------------------------
#define STAGE_U(panel, ldsArr, T, h, pb)                                       \
    {                                                                          \
        const int tc = (T) < NT ? (T) : (NT - 1);                              \
        const size_t kOff = (size_t)tc * 128;                                  \
        _Pragma("unroll")                                                      \
        for (int j = 0; j < 2; ++j) {                                          \
            __builtin_amdgcn_global_load_lds(                                  \
                (const __attribute__((address_space(1))) unsigned int*)        \
                    ((panel) + (size_t)((h) * 128 + j * 64 + srow8) * K + kOff + sblk), \
                (__attribute__((address_space(3))) unsigned int*)              \
                    ((ldsArr) + (pb) * 32768 + (h) * 16384 + j * 8192 + tid * 16), \
                16, 0, 0);                                                     \
        }                                                                      \
    }

// ---------------------------------------------------------------------------
// Kernel 3a (V1): round-6 4-phase structure, verbatim (+ mBase). Control arm.
// ---------------------------------------------------------------------------
__global__ __launch_bounds__(512, 2)
void gemm8_kernel(const signed char* __restrict__ qx,
                  const signed char* __restrict__ qw,
                  const float* __restrict__ a_w,
                  const float* __restrict__ bias,
                  const float* __restrict__ axp,
                  float* __restrict__ out,
                  int mBase)
{
    __shared__ signed char As[2 * 256 * 128];
    __shared__ signed char Bs[2 * 256 * 128];

    const int tid  = threadIdx.x;
    const int lane = tid & 63;
    const int wid  = tid >> 6;
    const int wm   = wid >> 2;
    const int wn   = wid & 3;

    const int bid = blockIdx.x;
    const int nb  = bid & 15;
    const int mb  = bid >> 4;

    const size_t K = DIN;
    constexpr int NT = DIN / 128;

    const int srow8 = tid >> 3;
    const int sblk  = ((tid & 7) ^ ((tid >> 4) & 7)) << 4;
    const signed char* aPanel = qx + (size_t)(mBase + mb * 256) * K;
    const signed char* bPanel = qw + (size_t)(nb * 256) * K;

    const int r15  = lane & 15;
    const int blk  = lane >> 4;
    const int key  = (r15 >> 1) & 7;
    const int sw0  = (blk ^ key) << 4;
    const int sw1  = ((blk ^ key) ^ 4) << 4;
    const int aRd0 = (wm * 128 + r15) * 128 + sw0;
    const int aRd1 = (wm * 128 + r15) * 128 + sw1;
    const int bRd0 = (wn * 64 + r15) * 128 + sw0;
    const int bRd1 = (wn * 64 + r15) * 128 + sw1;

    i32x4 acc[8][4];
    #pragma unroll
    for (int m = 0; m < 8; ++m)
        #pragma unroll
        for (int n = 0; n < 4; ++n) acc[m][n] = i32x4{0, 0, 0, 0};

    STAGE_U(bPanel, Bs, 0, 0, 0); STAGE_U(bPanel, Bs, 0, 1, 0);
    STAGE_U(aPanel, As, 0, 0, 0); STAGE_U(aPanel, As, 0, 1, 0);
    STAGE_U(bPanel, Bs, 1, 0, 1); STAGE_U(bPanel, Bs, 1, 1, 1);
    asm volatile("s_waitcnt vmcnt(4)" ::: "memory");
    __builtin_amdgcn_sched_barrier(0);
    __builtin_amdgcn_s_barrier();

    for (int t = 0; t < NT; ++t) {
        const int p = t & 1;
        const signed char* Ab = As + p * 32768;
        const signed char* Bb = Bs + p * 32768;
        i32x4 bf0[4], bf1[4], af0[4], af1[4], af2[4], af3[4];

        #pragma unroll
        for (int n = 0; n < 4; ++n) bf0[n] = *(const i32x4*)(Bb + bRd0 + n * 2048);
        #pragma unroll
        for (int m = 0; m < 4; ++m) af0[m] = *(const i32x4*)(Ab + aRd0 + m * 2048);
        __builtin_amdgcn_sched_barrier(0);
        #pragma unroll
        for (int m = 0; m < 4; ++m) af2[m] = *(const i32x4*)(Ab + aRd0 + 8192 + m * 2048);
        STAGE_U(aPanel, As, t + 1, 0, p ^ 1);
        __builtin_amdgcn_s_barrier();
        asm volatile("s_waitcnt lgkmcnt(4)" ::: "memory");
        __builtin_amdgcn_sched_barrier(0);
        __builtin_amdgcn_s_setprio(1);
        #pragma unroll
        for (int m = 0; m < 4; ++m)
            #pragma unroll
            for (int n = 0; n < 4; ++n)
                acc[m][n] = __builtin_amdgcn_mfma_i32_16x16x64_i8(af0[m], bf0[n], acc[m][n], 0, 0, 0);
        __builtin_amdgcn_s_setprio(0);
        __builtin_amdgcn_sched_barrier(0);
        __builtin_amdgcn_s_barrier();

        #pragma unroll
        for (int n = 0; n < 4; ++n) bf1[n] = *(const i32x4*)(Bb + bRd1 + n * 2048);
        #pragma unroll
        for (int m = 0; m < 4; ++m) af1[m] = *(const i32x4*)(Ab + aRd1 + m * 2048);
        __builtin_amdgcn_sched_barrier(0);
        #pragma unroll
        for (int m = 0; m < 4; ++m) af3[m] = *(const i32x4*)(Ab + aRd1 + 8192 + m * 2048);
        STAGE_U(aPanel, As, t + 1, 1, p ^ 1);
        __builtin_amdgcn_s_barrier();
        asm volatile("s_waitcnt lgkmcnt(4)" ::: "memory");
        __builtin_amdgcn_sched_barrier(0);
        __builtin_amdgcn_s_setprio(1);
        #pragma unroll
        for (int m = 0; m < 4; ++m)
            #pragma unroll
            for (int n = 0; n < 4; ++n)
                acc[m][n] = __builtin_amdgcn_mfma_i32_16x16x64_i8(af1[m], bf1[n], acc[m][n], 0, 0, 0);
        __builtin_amdgcn_s_setprio(0);
        __builtin_amdgcn_sched_barrier(0);
        __builtin_amdgcn_s_barrier();

        STAGE_U(bPanel, Bs, t + 2, 0, p);
        __builtin_amdgcn_s_barrier();
        asm volatile("s_waitcnt lgkmcnt(4)" ::: "memory");
        __builtin_amdgcn_sched_barrier(0);
        __builtin_amdgcn_s_setprio(1);
        #pragma unroll
        for (int m = 0; m < 4; ++m)
            #pragma unroll
            for (int n = 0; n < 4; ++n)
                acc[m + 4][n] = __builtin_amdgcn_mfma_i32_16x16x64_i8(af2[m], bf0[n], acc[m + 4][n], 0, 0, 0);
        __builtin_amdgcn_s_setprio(0);
        __builtin_amdgcn_sched_barrier(0);
        __builtin_amdgcn_s_barrier();

        STAGE_U(bPanel, Bs, t + 2, 1, p);
        __builtin_amdgcn_s_barrier();
        asm volatile("s_waitcnt lgkmcnt(0)" ::: "memory");
        __builtin_amdgcn_sched_barrier(0);
        __builtin_amdgcn_s_setprio(1);
        #pragma unroll
        for (int m = 0; m < 4; ++m)
            #pragma unroll
            for (int n = 0; n < 4; ++n)
                acc[m + 4][n] = __builtin_amdgcn_mfma_i32_16x16x64_i8(af3[m], bf1[n], acc[m + 4][n], 0, 0, 0);
        __builtin_amdgcn_s_setprio(0);
        __builtin_amdgcn_sched_barrier(0);
        asm volatile("s_waitcnt vmcnt(4)" ::: "memory");
        __builtin_amdgcn_sched_barrier(0);
        __builtin_amdgcn_s_barrier();
    }

    asm volatile("s_waitcnt vmcnt(0)" ::: "memory");

    const float ax = fmaxf(axp[0], EPSF);
    #pragma unroll
    for (int n = 0; n < 4; ++n) {
        const int o = nb * 256 + wn * 64 + n * 16 + r15;
        const float scale = ax * a_w[o] * (1.0f / 16129.0f);
        const float bs = bias[o];
        #pragma unroll
        for (int m = 0; m < 8; ++m) {
            const int t0 = mBase + mb * 256 + wm * 128 + m * 16 + (blk << 2);
            float* op = out + (size_t)t0 * DOUT + o;
            #pragma unroll
            for (int r = 0; r < 4; ++r)
                op[(size_t)r * DOUT] = (float)acc[m][n][r] * scale + bs;
        }
    }
}

// ---------------------------------------------------------------------------
// Kernel 3b (V2): 2-barrier counted-lgkm schedule. All 24 ds_reads issued
// up-front in wait-order {bf0,af0 | af2 | bf1,af1 | af3}; MFMA clusters gated
// by lgkmcnt(15)/(4)/—/(0) so reads drain UNDER MFMA execution; barriers only
// where correctness requires: mid-tile (all B-reads done -> stage B(t+2) into
// Bs[p] safe) and tile end (vmcnt(4) -> buffers resident; all reads of p^1
// done -> stage A into p^1 safe next tile). Same vmcnt bookkeeping as V1.
// ---------------------------------------------------------------------------
__global__ __launch_bounds__(512, 2)
void gemm8v2_kernel(const signed char* __restrict__ qx,
                    const signed char* __restrict__ qw,
                    const float* __restrict__ a_w,
                    const float* __restrict__ bias,
                    const float* __restrict__ axp,
                    float* __restrict__ out,
                    int mBase)
{
    __shared__ signed char As[2 * 256 * 128];
    __shared__ signed char Bs[2 * 256 * 128];

    const int tid  = threadIdx.x;
    const int lane = tid & 63;
    const int wid  = tid >> 6;
    const int wm   = wid >> 2;
    const int wn   = wid & 3;

    const int bid = blockIdx.x;
    const int nb  = bid & 15;
    const int mb  = bid >> 4;

    const size_t K = DIN;
    constexpr int NT = DIN / 128;

    const int srow8 = tid >> 3;
    const int sblk  = ((tid & 7) ^ ((tid >> 4) & 7)) << 4;
    const signed char* aPanel = qx + (size_t)(mBase + mb * 256) * K;
    const signed char* bPanel = qw + (size_t)(nb * 256) * K;

    const int r15  = lane & 15;
    const int blk  = lane >> 4;
    const int key  = (r15 >> 1) & 7;
    const int sw0  = (blk ^ key) << 4;
    const int sw1  = ((blk ^ key) ^ 4) << 4;
    const int aRd0 = (wm * 128 + r15) * 128 + sw0;
    const int aRd1 = (wm * 128 + r15) * 128 + sw1;
    const int bRd0 = (wn * 64 + r15) * 128 + sw0;
    const int bRd1 = (wn * 64 + r15) * 128 + sw1;

    i32x4 acc[8][4];
    #pragma unroll
    for (int m = 0; m < 8; ++m)
        #pragma unroll
        for (int n = 0; n < 4; ++n) acc[m][n] = i32x4{0, 0, 0, 0};

    STAGE_U(bPanel, Bs, 0, 0, 0); STAGE_U(bPanel, Bs, 0, 1, 0);
    STAGE_U(aPanel, As, 0, 0, 0); STAGE_U(aPanel, As, 0, 1, 0);
    STAGE_U(bPanel, Bs, 1, 0, 1); STAGE_U(bPanel, Bs, 1, 1, 1);
    asm volatile("s_waitcnt vmcnt(4)" ::: "memory");
    __builtin_amdgcn_sched_barrier(0);
    __builtin_amdgcn_s_barrier();

    for (int t = 0; t < NT; ++t) {
        const int p = t & 1;
        const signed char* Ab = As + p * 32768;
        const signed char* Bb = Bs + p * 32768;
        i32x4 bf0[4], bf1[4], af0[4], af1[4], af2[4], af3[4];

        // ---- issue all 24 ds_reads in wait-order (groups pinned) ----
        #pragma unroll
        for (int n = 0; n < 4; ++n) bf0[n] = *(const i32x4*)(Bb + bRd0 + n * 2048);
        #pragma unroll
        for (int m = 0; m < 4; ++m) af0[m] = *(const i32x4*)(Ab + aRd0 + m * 2048);
        __builtin_amdgcn_sched_barrier(0);   // group 1: bf0,af0 (8)
        #pragma unroll
        for (int m = 0; m < 4; ++m) af2[m] = *(const i32x4*)(Ab + aRd0 + 8192 + m * 2048);
        __builtin_amdgcn_sched_barrier(0);   // group 2: af2 (4)
        #pragma unroll
        for (int n = 0; n < 4; ++n) bf1[n] = *(const i32x4*)(Bb + bRd1 + n * 2048);
        #pragma unroll
        for (int m = 0; m < 4; ++m) af1[m] = *(const i32x4*)(Ab + aRd1 + m * 2048);
        __builtin_amdgcn_sched_barrier(0);   // group 3: bf1,af1 (8)
        #pragma unroll
        for (int m = 0; m < 4; ++m) af3[m] = *(const i32x4*)(Ab + aRd1 + 8192 + m * 2048);
        __builtin_amdgcn_sched_barrier(0);   // group 4: af3 (4)

        // ---- stage A(t+1) both halves into buf p^1 (DMA, overlaps all) ----
        STAGE_U(aPanel, As, t + 1, 0, p ^ 1);
        STAGE_U(aPanel, As, t + 1, 1, p ^ 1);

        // ---- MFMA-0: needs bf0,af0 (first 8 of 24) -> wait to <=15 ----
        asm volatile("s_waitcnt lgkmcnt(15)" ::: "memory");
        __builtin_amdgcn_sched_barrier(0);
        __builtin_amdgcn_s_setprio(1);
        #pragma unroll
        for (int m = 0; m < 4; ++m)
            #pragma unroll
            for (int n = 0; n < 4; ++n)
                acc[m][n] = __builtin_amdgcn_mfma_i32_16x16x64_i8(af0[m], bf0[n], acc[m][n], 0, 0, 0);
        __builtin_amdgcn_s_setprio(0);

        // ---- MFMA-1: needs bf1,af1 (through read 20) -> wait to <=4 ----
        asm volatile("s_waitcnt lgkmcnt(4)" ::: "memory");
        __builtin_amdgcn_sched_barrier(0);
        __builtin_amdgcn_s_setprio(1);
        #pragma unroll
        for (int m = 0; m < 4; ++m)
            #pragma unroll
            for (int n = 0; n < 4; ++n)
                acc[m][n] = __builtin_amdgcn_mfma_i32_16x16x64_i8(af1[m], bf1[n], acc[m][n], 0, 0, 0);
        __builtin_amdgcn_s_setprio(0);
        __builtin_amdgcn_sched_barrier(0);

        // ---- mid-tile barrier: every wave past lgkm(4) => all B-reads of
        //      buf p complete => staging B(t+2) into Bs[p] is safe ----
        __builtin_amdgcn_s_barrier();
        STAGE_U(bPanel, Bs, t + 2, 0, p);
        STAGE_U(bPanel, Bs, t + 2, 1, p);

        // ---- MFMA-2: af2,bf0 already resident (lgkm<=4 guarantees) ----
        __builtin_amdgcn_s_setprio(1);
        #pragma unroll
        for (int m = 0; m < 4; ++m)
            #pragma unroll
            for (int n = 0; n < 4; ++n)
                acc[m + 4][n] = __builtin_amdgcn_mfma_i32_16x16x64_i8(af2[m], bf0[n], acc[m + 4][n], 0, 0, 0);
        __builtin_amdgcn_s_setprio(0);

        // ---- MFMA-3: needs af3 -> drain ----
        asm volatile("s_waitcnt lgkmcnt(0)" ::: "memory");
        __builtin_amdgcn_sched_barrier(0);
        __builtin_amdgcn_s_setprio(1);
        #pragma unroll
        for (int m = 0; m < 4; ++m)
            #pragma unroll
            for (int n = 0; n < 4; ++n)
                acc[m + 4][n] = __builtin_amdgcn_mfma_i32_16x16x64_i8(af3[m], bf1[n], acc[m + 4][n], 0, 0, 0);
        __builtin_amdgcn_s_setprio(0);
        __builtin_amdgcn_sched_barrier(0);

        // ---- tile end: A(t+1),B(t+1) resident (retire to 4 outstanding) ----
        asm volatile("s_waitcnt vmcnt(4)" ::: "memory");
        __builtin_amdgcn_sched_barrier(0);
        __builtin_amdgcn_s_barrier();
    }

    asm volatile("s_waitcnt vmcnt(0)" ::: "memory");

    const float ax = fmaxf(axp[0], EPSF);
    #pragma unroll
    for (int n = 0; n < 4; ++n) {
        const int o = nb * 256 + wn * 64 + n * 16 + r15;
        const float scale = ax * a_w[o] * (1.0f / 16129.0f);
        const float bs = bias[o];
        #pragma unroll
        for (int m = 0; m < 8; ++m) {
            const int t0 = mBase + mb * 256 + wm * 128 + m * 16 + (blk << 2);
            float* op = out + (size_t)t0 * DOUT + o;
            #pragma unroll
            for (int r = 0; r < 4; ++r)
                op[(size_t)r * DOUT] = (float)acc[m][n][r] * scale + bs;
        }
    }
}

#undef STAGE_U

// ---------------------------------------------------------------------------
extern "C" void kernel_launch(void* const* d_in, const int* in_sizes, int n_in,
                              void* d_out, int out_size, void* d_ws, size_t ws_size,
                              hipStream_t stream)
{
    const float* x    = (const float*)d_in[0];
    const float* W    = (const float*)d_in[1];
    const float* lA   = (const float*)d_in[2];
    const float* lB   = (const float*)d_in[3];
    const float* bias = (const float*)d_in[4];
    const float* ax   = (const float*)d_in[5];
    float* out        = (float*)d_out;

    // workspace: qx (64MB) | qw (16MB) | a_w (16KB)
    signed char* qx = (signed char*)d_ws;
    signed char* qw = qx + (size_t)TDIM * DIN;
    float* a_w      = (float*)(qw + (size_t)DOUT * DIN);

    wquant_kernel<<<DOUT / 4, 256, 0, stream>>>(W, lA, lB, a_w, qw);

    const int xblocks = (int)(((size_t)TDIM * DIN) / (16 * 256));  // 16384
    xquant_kernel<<<xblocks, 256, 0, stream>>>(x, ax, (unsigned int*)qx);

    // Within-run A/B: rows [0,8192) = V1 (round-6 control), rows [8192,16384)
    // = V2 (2-barrier counted-lgkm). rocprof reports dispatches separately.
    gemm8_kernel<<<(8192 / 256) * (DOUT / 256), 512, 0, stream>>>(
        qx, qw, a_w, bias, ax, out, 0);
    gemm8v2_kernel<<<(8192 / 256) * (DOUT / 256), 512, 0, stream>>>(
        qx, qw, a_w, bias, ax, out, 8192);
}

// Round 8
// 403.941 us; speedup vs baseline: 1.3359x; 1.0146x over previous
//
#include <hip/hip_runtime.h>
#include <hip/hip_bf16.h>

// Problem constants (fixed by setup_inputs)
constexpr int TDIM = 16384;
constexpr int DIN  = 4096;
constexpr int DOUT = 4096;
constexpr int RNK  = 32;
constexpr float EPSF = 1e-8f;

using i32x4 = __attribute__((ext_vector_type(4))) int;

// ---------------------------------------------------------------------------
// Kernel 1: weight_eff = W + loraB @ loraA  -> per-row absmax -> int8 quantize
// (unchanged from round 2)
// ---------------------------------------------------------------------------
__global__ __launch_bounds__(256)
void wquant_kernel(const float* __restrict__ W,
                   const float* __restrict__ Amat,   // [32, 4096]
                   const float* __restrict__ Bmat,   // [4096, 32]
                   float* __restrict__ a_w,          // [4096]
                   signed char* __restrict__ qw)     // [4096, 4096]
{
    const int tid = threadIdx.x;
    const int o0  = blockIdx.x * 4;

    __shared__ float Bsh[4][32];
    __shared__ float red[4][4];
    __shared__ float awsh[4];

    if (tid < 128) {
        int r = tid >> 5, c = tid & 31;
        Bsh[r][c] = Bmat[(size_t)(o0 + r) * RNK + c];
    }
    __syncthreads();

    float4 acc[4][4];
    #pragma unroll
    for (int r = 0; r < 4; ++r)
        #pragma unroll
        for (int c = 0; c < 4; ++c)
            acc[r][c] = *(const float4*)(W + (size_t)(o0 + r) * DIN + c * 1024 + tid * 4);

    #pragma unroll 4
    for (int k = 0; k < RNK; ++k) {
        float4 a[4];
        #pragma unroll
        for (int c = 0; c < 4; ++c)
            a[c] = *(const float4*)(Amat + (size_t)k * DIN + c * 1024 + tid * 4);
        #pragma unroll
        for (int r = 0; r < 4; ++r) {
            const float b = Bsh[r][k];
            #pragma unroll
            for (int c = 0; c < 4; ++c) {
                acc[r][c].x += b * a[c].x; acc[r][c].y += b * a[c].y;
                acc[r][c].z += b * a[c].z; acc[r][c].w += b * a[c].w;
            }
        }
    }

    const int wid = tid >> 6;
    #pragma unroll
    for (int r = 0; r < 4; ++r) {
        float m = 0.f;
        #pragma unroll
        for (int c = 0; c < 4; ++c) {
            float4 v = acc[r][c];
            m = fmaxf(m, fmaxf(fmaxf(fabsf(v.x), fabsf(v.y)),
                               fmaxf(fabsf(v.z), fabsf(v.w))));
        }
        for (int off = 1; off < 64; off <<= 1)
            m = fmaxf(m, __shfl_xor(m, off));
        if ((tid & 63) == 0) red[wid][r] = m;
    }
    __syncthreads();
    if (tid < 4) {
        float m = fmaxf(fmaxf(red[0][tid], red[1][tid]),
                        fmaxf(red[2][tid], red[3][tid]));
        float aw = m + EPSF;
        awsh[tid] = aw;
        a_w[o0 + tid] = aw;
    }
    __syncthreads();

    #pragma unroll
    for (int r = 0; r < 4; ++r) {
        const float aw = awsh[r];
        #pragma unroll
        for (int c = 0; c < 4; ++c) {
            float4 v = acc[r][c];
            int q0 = __float2int_rn((v.x / aw) * 127.0f);
            int q1 = __float2int_rn((v.y / aw) * 127.0f);
            int q2 = __float2int_rn((v.z / aw) * 127.0f);
            int q3 = __float2int_rn((v.w / aw) * 127.0f);
            unsigned int packed = (q0 & 0xff) | ((q1 & 0xff) << 8) |
                                  ((q2 & 0xff) << 16) | ((q3 & 0xff) << 24);
            *(unsigned int*)(qw + (size_t)(o0 + r) * DIN + c * 1024 + tid * 4) = packed;
        }
    }
}

// ---------------------------------------------------------------------------
// Kernel 2: x quantize (unchanged from round 2 — coalesced)
// ---------------------------------------------------------------------------
__global__ __launch_bounds__(256)
void xquant_kernel(const float* __restrict__ x,
                   const float* __restrict__ axp,
                   unsigned int* __restrict__ qx)
{
    const float inv = 1.0f / fmaxf(axp[0], EPSF);
    const size_t base = (size_t)blockIdx.x * 1024 + threadIdx.x;
    const float4* xv = (const float4*)x;

    float4 v[4];
    #pragma unroll
    for (int j = 0; j < 4; ++j)
        v[j] = xv[base + j * 256];

    #pragma unroll
    for (int j = 0; j < 4; ++j) {
        int q0 = __float2int_rn(fminf(fmaxf(v[j].x * inv, -1.f), 1.f) * 127.0f);
        int q1 = __float2int_rn(fminf(fmaxf(v[j].y * inv, -1.f), 1.f) * 127.0f);
        int q2 = __float2int_rn(fminf(fmaxf(v[j].z * inv, -1.f), 1.f) * 127.0f);
        int q3 = __float2int_rn(fminf(fmaxf(v[j].w * inv, -1.f), 1.f) * 127.0f);
        qx[base + j * 256] = (q0 & 0xff) | ((q1 & 0xff) << 8) |
                             ((q2 & 0xff) << 16) | ((q3 & 0xff) << 24);
    }
}

// ---------------------------------------------------------------------------
// Kernel 3 (V3): 256x256 i8 GEMM, ONE barrier per K-tile.
// A double-buffered (64KB), B TRIPLE-buffered (48KB) -> 112 KiB LDS.
// Per tile t: issue all 24 ds_reads (wait-ordered groups) + all 8 DMA loads
// (A(t+1) -> A[p^1], B(t+2) -> B[(t+2)%3]; both targets' last readers were
// fenced by the tile-(t-1)-end barrier), then 4 MFMA clusters gated by
// counted lgkmcnt(15)/(4)/none/(0); tile-end vmcnt(4) + single s_barrier.
// vmcnt invariant: tile-start outstanding = B(t+1)x4; +8 issued; vmcnt(4)
// retires B(t+1)+A(t+1), floats B(t+2).
// ---------------------------------------------------------------------------
__global__ __launch_bounds__(512, 2)
void gemm8v3_kernel(const signed char* __restrict__ qx,
                    const signed char* __restrict__ qw,
                    const float* __restrict__ a_w,
                    const float* __restrict__ bias,
                    const float* __restrict__ axp,
                    float* __restrict__ out)
{
    __shared__ signed char As[2 * 256 * 128];   // 64 KB
    __shared__ signed char Bs[3 * 256 * 128];   // 96 KB... no: 3*32KB = 96KB
    // NOTE: 64 + 96 = 160KB would exceed budget with other usage; B tile is
    // 256x128B = 32KB -> 3 bufs = 96KB; A 2 bufs = 64KB; total 160KB == max.
    // Keep within 160KiB: gfx950 allows 160KB/workgroup; LDS_Block_Size will
    // show 163840. Occupancy unchanged (already 1 block/CU).

    const int tid  = threadIdx.x;
    const int lane = tid & 63;
    const int wid  = tid >> 6;
    const int wm   = wid >> 2;
    const int wn   = wid & 3;

    const int bid = blockIdx.x;
    const int nb  = bid & 15;
    const int mb  = bid >> 4;

    const size_t K = DIN;
    constexpr int NT = DIN / 128;   // 32 K-tiles

    const int srow8 = tid >> 3;
    const int sblk  = ((tid & 7) ^ ((tid >> 4) & 7)) << 4;
    const signed char* aPanel = qx + (size_t)(mb * 256) * K;
    const signed char* bPanel = qw + (size_t)(nb * 256) * K;

    const int r15  = lane & 15;
    const int blk  = lane >> 4;
    const int key  = (r15 >> 1) & 7;
    const int sw0  = (blk ^ key) << 4;
    const int sw1  = ((blk ^ key) ^ 4) << 4;
    const int aRd0 = (wm * 128 + r15) * 128 + sw0;
    const int aRd1 = (wm * 128 + r15) * 128 + sw1;
    const int bRd0 = (wn * 64 + r15) * 128 + sw0;
    const int bRd1 = (wn * 64 + r15) * 128 + sw1;

    i32x4 acc[8][4];
    #pragma unroll
    for (int m = 0; m < 8; ++m)
        #pragma unroll
        for (int n = 0; n < 4; ++n) acc[m][n] = i32x4{0, 0, 0, 0};

#define STAGE_U(panel, ldsArr, T, h, pb)                                       \
    {                                                                          \
        const int tc = (T) < NT ? (T) : (NT - 1);                              \
        const size_t kOff = (size_t)tc * 128;                                  \
        _Pragma("unroll")                                                      \
        for (int j = 0; j < 2; ++j) {                                          \
            __builtin_amdgcn_global_load_lds(                                  \
                (const __attribute__((address_space(1))) unsigned int*)        \
                    ((panel) + (size_t)((h) * 128 + j * 64 + srow8) * K + kOff + sblk), \
                (__attribute__((address_space(3))) unsigned int*)              \
                    ((ldsArr) + (pb) * 32768 + (h) * 16384 + j * 8192 + tid * 16), \
                16, 0, 0);                                                     \
        }                                                                      \
    }

    // ---- prologue: B(0)->B0, A(0)->A0, B(1)->B1 (12 loads); vmcnt(4)
    //      retires B(0),A(0); leaves B(1) outstanding (= loop invariant) ----
    STAGE_U(bPanel, Bs, 0, 0, 0); STAGE_U(bPanel, Bs, 0, 1, 0);
    STAGE_U(aPanel, As, 0, 0, 0); STAGE_U(aPanel, As, 0, 1, 0);
    STAGE_U(bPanel, Bs, 1, 0, 1); STAGE_U(bPanel, Bs, 1, 1, 1);
    asm volatile("s_waitcnt vmcnt(4)" ::: "memory");
    __builtin_amdgcn_sched_barrier(0);
    __builtin_amdgcn_s_barrier();

    int q = 0;   // B read buffer = t % 3 (incremented mod 3 each tile)
    for (int t = 0; t < NT; ++t) {
        const int p  = t & 1;
        const int qc = (q == 0) ? 2 : q - 1;   // (t+2) % 3
        const signed char* Ab = As + p * 32768;
        const signed char* Bb = Bs + q * 32768;
        i32x4 bf0[4], bf1[4], af0[4], af1[4], af2[4], af3[4];

        // ---- issue all 24 ds_reads in wait-order (groups pinned) ----
        #pragma unroll
        for (int n = 0; n < 4; ++n) bf0[n] = *(const i32x4*)(Bb + bRd0 + n * 2048);
        #pragma unroll
        for (int m = 0; m < 4; ++m) af0[m] = *(const i32x4*)(Ab + aRd0 + m * 2048);
        __builtin_amdgcn_sched_barrier(0);   // group 1: bf0,af0 (8)
        #pragma unroll
        for (int m = 0; m < 4; ++m) af2[m] = *(const i32x4*)(Ab + aRd0 + 8192 + m * 2048);
        __builtin_amdgcn_sched_barrier(0);   // group 2: af2 (12)
        #pragma unroll
        for (int n = 0; n < 4; ++n) bf1[n] = *(const i32x4*)(Bb + bRd1 + n * 2048);
        #pragma unroll
        for (int m = 0; m < 4; ++m) af1[m] = *(const i32x4*)(Ab + aRd1 + m * 2048);
        __builtin_amdgcn_sched_barrier(0);   // group 3: bf1,af1 (20)
        #pragma unroll
        for (int m = 0; m < 4; ++m) af3[m] = *(const i32x4*)(Ab + aRd1 + 8192 + m * 2048);
        __builtin_amdgcn_sched_barrier(0);   // group 4: af3 (24)

        // ---- issue ALL staging DMA now (targets fenced by last barrier) ----
        STAGE_U(aPanel, As, t + 1, 0, p ^ 1);
        STAGE_U(aPanel, As, t + 1, 1, p ^ 1);
        STAGE_U(bPanel, Bs, t + 2, 0, qc);
        STAGE_U(bPanel, Bs, t + 2, 1, qc);

        // ---- MFMA-0: needs bf0,af0 (oldest 8 of 24) ----
        asm volatile("s_waitcnt lgkmcnt(15)" ::: "memory");
        __builtin_amdgcn_sched_barrier(0);
        __builtin_amdgcn_s_setprio(1);
        #pragma unroll
        for (int m = 0; m < 4; ++m)
            #pragma unroll
            for (int n = 0; n < 4; ++n)
                acc[m][n] = __builtin_amdgcn_mfma_i32_16x16x64_i8(af0[m], bf0[n], acc[m][n], 0, 0, 0);
        __builtin_amdgcn_s_setprio(0);

        // ---- MFMA-1: needs through af1 (oldest 20) ----
        asm volatile("s_waitcnt lgkmcnt(4)" ::: "memory");
        __builtin_amdgcn_sched_barrier(0);
        __builtin_amdgcn_s_setprio(1);
        #pragma unroll
        for (int m = 0; m < 4; ++m)
            #pragma unroll
            for (int n = 0; n < 4; ++n)
                acc[m][n] = __builtin_amdgcn_mfma_i32_16x16x64_i8(af1[m], bf1[n], acc[m][n], 0, 0, 0);
        __builtin_amdgcn_s_setprio(0);
        __builtin_amdgcn_sched_barrier(0);

        // ---- MFMA-2: af2 (pos 9-12) already covered by lgkm(4) ----
        __builtin_amdgcn_s_setprio(1);
        #pragma unroll
        for (int m = 0; m < 4; ++m)
            #pragma unroll
            for (int n = 0; n < 4; ++n)
                acc[m + 4][n] = __builtin_amdgcn_mfma_i32_16x16x64_i8(af2[m], bf0[n], acc[m + 4][n], 0, 0, 0);
        __builtin_amdgcn_s_setprio(0);

        // ---- MFMA-3: needs af3 -> drain ----
        asm volatile("s_waitcnt lgkmcnt(0)" ::: "memory");
        __builtin_amdgcn_sched_barrier(0);
        __builtin_amdgcn_s_setprio(1);
        #pragma unroll
        for (int m = 0; m < 4; ++m)
            #pragma unroll
            for (int n = 0; n < 4; ++n)
                acc[m + 4][n] = __builtin_amdgcn_mfma_i32_16x16x64_i8(af3[m], bf1[n], acc[m + 4][n], 0, 0, 0);
        __builtin_amdgcn_s_setprio(0);
        __builtin_amdgcn_sched_barrier(0);

        // ---- tile end: A(t+1),B(t+1) resident; B(t+2) stays in flight ----
        asm volatile("s_waitcnt vmcnt(4)" ::: "memory");
        __builtin_amdgcn_sched_barrier(0);
        __builtin_amdgcn_s_barrier();

        q = (q == 2) ? 0 : q + 1;
    }
#undef STAGE_U

    asm volatile("s_waitcnt vmcnt(0)" ::: "memory");

    // ---- epilogue: C/D layout col=lane&15, row=(lane>>4)*4+reg ----
    const float ax = fmaxf(axp[0], EPSF);
    #pragma unroll
    for (int n = 0; n < 4; ++n) {
        const int o = nb * 256 + wn * 64 + n * 16 + r15;
        const float scale = ax * a_w[o] * (1.0f / 16129.0f);
        const float bs = bias[o];
        #pragma unroll
        for (int m = 0; m < 8; ++m) {
            const int t0 = mb * 256 + wm * 128 + m * 16 + (blk << 2);
            float* op = out + (size_t)t0 * DOUT + o;
            #pragma unroll
            for (int r = 0; r < 4; ++r)
                op[(size_t)r * DOUT] = (float)acc[m][n][r] * scale + bs;
        }
    }
}

// ---------------------------------------------------------------------------
extern "C" void kernel_launch(void* const* d_in, const int* in_sizes, int n_in,
                              void* d_out, int out_size, void* d_ws, size_t ws_size,
                              hipStream_t stream)
{
    const float* x    = (const float*)d_in[0];
    const float* W    = (const float*)d_in[1];
    const float* lA   = (const float*)d_in[2];
    const float* lB   = (const float*)d_in[3];
    const float* bias = (const float*)d_in[4];
    const float* ax   = (const float*)d_in[5];
    float* out        = (float*)d_out;

    // workspace: qx (64MB) | qw (16MB) | a_w (16KB)
    signed char* qx = (signed char*)d_ws;
    signed char* qw = qx + (size_t)TDIM * DIN;
    float* a_w      = (float*)(qw + (size_t)DOUT * DIN);

    wquant_kernel<<<DOUT / 4, 256, 0, stream>>>(W, lA, lB, a_w, qw);

    const int xblocks = (int)(((size_t)TDIM * DIN) / (16 * 256));  // 16384
    xquant_kernel<<<xblocks, 256, 0, stream>>>(x, ax, (unsigned int*)qx);

    gemm8v3_kernel<<<(TDIM / 256) * (DOUT / 256), 512, 0, stream>>>(
        qx, qw, a_w, bias, ax, out);
}